// Round 1
// baseline (389.325 us; speedup 1.0000x reference)
//
#include <hip/hip_runtime.h>
#include <hip/hip_bf16.h>

#define B_ 4
#define S_ 2048
#define D_ 1024
#define H_ 16
#define DH_ 64

typedef __attribute__((ext_vector_type(8))) short bf16x8;
typedef __attribute__((ext_vector_type(4))) float f32x4;

__device__ __forceinline__ unsigned short f2bf(float f) {
  unsigned int u = __float_as_uint(f);
  u += 0x7FFFu + ((u >> 16) & 1u);
  return (unsigned short)(u >> 16);
}

// ---------------- prep kernels ----------------

// cast K (fp32 [B,S,D]) -> bf16, layout unchanged
__global__ void cast_k_kernel(const float* __restrict__ k, ushort* __restrict__ Kb) {
  int i = blockIdx.x * 256 + threadIdx.x;            // 2,097,152 threads, 4 elems each
  float4 a = ((const float4*)k)[i];
  ushort4 r;
  r.x = f2bf(a.x); r.y = f2bf(a.y); r.z = f2bf(a.z); r.w = f2bf(a.w);
  ((ushort4*)Kb)[i] = r;
}

// cast W_O (fp32 [D,D]) -> bf16
__global__ void cast_w_kernel(const float* __restrict__ w, ushort* __restrict__ Wb) {
  int i = blockIdx.x * 256 + threadIdx.x;            // 262,144 threads
  float4 a = ((const float4*)w)[i];
  ushort4 r;
  r.x = f2bf(a.x); r.y = f2bf(a.y); r.z = f2bf(a.z); r.w = f2bf(a.w);
  ((ushort4*)Wb)[i] = r;
}

// padding mask (int32 0/1, [B,S]) -> float addend (0 or -1e30)
__global__ void mask_kernel(const int* __restrict__ kpm, float* __restrict__ MF) {
  int i = blockIdx.x * 256 + threadIdx.x;            // 8192
  MF[i] = kpm[i] ? -1e30f : 0.0f;
}

// V (fp32 [B,S,H*DH]) -> Vt (bf16 [B,H,DH,S])  tiled transpose
__global__ void transpose_v_kernel(const float* __restrict__ v, ushort* __restrict__ Vt) {
  __shared__ ushort tile[64][68];
  int bh = blockIdx.x >> 5;                 // 0..63 = b*H + h
  int s0 = (blockIdx.x & 31) << 6;          // s tile base
  int b = bh >> 4, h = bh & 15;
  int t = threadIdx.x;
#pragma unroll
  for (int it = 0; it < 16; ++it) {
    int r = it * 4 + (t >> 6);              // s row 0..63
    int c = t & 63;                         // d 0..63
    float x = v[(size_t)(b * S_ + s0 + r) * D_ + h * DH_ + c];
    tile[r][c] = f2bf(x);
  }
  __syncthreads();
#pragma unroll
  for (int it = 0; it < 16; ++it) {
    int d = it * 4 + (t >> 6);
    int s = t & 63;
    Vt[(size_t)(bh * DH_ + d) * S_ + s0 + s] = tile[s][d];
  }
}

// ---------------- flash attention ----------------
// grid (32 qtiles, H, B), 256 threads = 4 waves, wave owns 16 q-rows.
__global__ __launch_bounds__(256) void attn_fwd(
    const float* __restrict__ q, const ushort* __restrict__ Kb,
    const ushort* __restrict__ Vt, const float* __restrict__ MF,
    ushort* __restrict__ AO) {
  __shared__ ushort Kl[32 * 72];        // K tile: 32 keys x 64 d, row stride 72 elems (144B)
  __shared__ ushort Vl[64 * 40];        // V^T tile: 64 d x 32 keys, row stride 40 elems (80B)
  __shared__ ushort Pl[4][16 * 40];     // per-wave P tile: 16 q x 32 k, row stride 40

  const int b = blockIdx.z, h = blockIdx.y;
  const int q0 = blockIdx.x * 64;
  const int tid = threadIdx.x;
  const int wv = tid >> 6, ln = tid & 63;
  const int r16 = ln & 15, g = ln >> 4;
  const int qbase = q0 + wv * 16;

  // Q fragments (read fp32 once, convert in-register)
  bf16x8 aq[2];
  {
    const float* qp = q + (size_t)(b * S_ + qbase + r16) * D_ + h * DH_ + g * 8;
#pragma unroll
    for (int ks = 0; ks < 2; ++ks) {
      float4 x0 = *(const float4*)(qp + ks * 32);
      float4 x1 = *(const float4*)(qp + ks * 32 + 4);
      bf16x8 t;
      t[0] = (short)f2bf(x0.x); t[1] = (short)f2bf(x0.y);
      t[2] = (short)f2bf(x0.z); t[3] = (short)f2bf(x0.w);
      t[4] = (short)f2bf(x1.x); t[5] = (short)f2bf(x1.y);
      t[6] = (short)f2bf(x1.z); t[7] = (short)f2bf(x1.w);
      aq[ks] = t;
    }
  }

  f32x4 o[4] = {};
  float m[4], l[4];
#pragma unroll
  for (int j = 0; j < 4; ++j) { m[j] = -1e30f; l[j] = 0.0f; }

  const int nkb = (q0 + 64) >> 5;          // 32-key blocks needed by this block
  const int my_qmax = qbase + 15;

  for (int kb = 0; kb < nkb; ++kb) {
    const int k0 = kb << 5;
    // cooperative staging: K tile (32x64) and V^T tile (64x32)
    {
      int row = tid >> 3, seg = tid & 7;   // 32 rows x 8 segs of 8 bf16
      *(bf16x8*)(&Kl[row * 72 + seg * 8]) =
          *(const bf16x8*)(Kb + (size_t)(b * S_ + k0 + row) * D_ + h * DH_ + seg * 8);
      int d = tid >> 2, s4 = tid & 3;      // 64 rows x 4 segs
      *(bf16x8*)(&Vl[d * 40 + s4 * 8]) =
          *(const bf16x8*)(Vt + (size_t)((b * H_ + h) * DH_ + d) * S_ + k0 + s4 * 8);
    }
    __syncthreads();

    if (k0 <= my_qmax) {
      f32x4 s0 = {}, s1 = {};
      bf16x8 bk00 = *(const bf16x8*)(&Kl[r16 * 72 + g * 8]);
      bf16x8 bk01 = *(const bf16x8*)(&Kl[r16 * 72 + 32 + g * 8]);
      bf16x8 bk10 = *(const bf16x8*)(&Kl[(16 + r16) * 72 + g * 8]);
      bf16x8 bk11 = *(const bf16x8*)(&Kl[(16 + r16) * 72 + 32 + g * 8]);
      s0 = __builtin_amdgcn_mfma_f32_16x16x32_bf16(aq[0], bk00, s0, 0, 0, 0);
      s0 = __builtin_amdgcn_mfma_f32_16x16x32_bf16(aq[1], bk01, s0, 0, 0, 0);
      s1 = __builtin_amdgcn_mfma_f32_16x16x32_bf16(aq[0], bk10, s1, 0, 0, 0);
      s1 = __builtin_amdgcn_mfma_f32_16x16x32_bf16(aq[1], bk11, s1, 0, 0, 0);

      const int c0 = k0 + r16, c1 = c0 + 16;
      const float pm0 = MF[b * S_ + c0];
      const float pm1 = MF[b * S_ + c1];
#pragma unroll
      for (int j = 0; j < 4; ++j) {
        const int rq = qbase + 4 * g + j;
        float v0 = (c0 <= rq) ? (s0[j] * 0.125f + pm0) : -1e30f;
        float v1 = (c1 <= rq) ? (s1[j] * 0.125f + pm1) : -1e30f;
        float tm = fmaxf(v0, v1);
        tm = fmaxf(tm, __shfl_xor(tm, 1));
        tm = fmaxf(tm, __shfl_xor(tm, 2));
        tm = fmaxf(tm, __shfl_xor(tm, 4));
        tm = fmaxf(tm, __shfl_xor(tm, 8));
        float mn = fmaxf(m[j], tm);
        float fac = __expf(m[j] - mn);
        float p0 = __expf(v0 - mn);
        float p1 = __expf(v1 - mn);
        float rs = p0 + p1;
        rs += __shfl_xor(rs, 1);
        rs += __shfl_xor(rs, 2);
        rs += __shfl_xor(rs, 4);
        rs += __shfl_xor(rs, 8);
        l[j] = l[j] * fac + rs;
        m[j] = mn;
        o[0][j] *= fac; o[1][j] *= fac; o[2][j] *= fac; o[3][j] *= fac;
        ushort* pr = &Pl[wv][(4 * g + j) * 40];
        pr[r16] = f2bf(p0);
        pr[16 + r16] = f2bf(p1);
      }
      asm volatile("s_waitcnt lgkmcnt(0)" ::: "memory");
      __builtin_amdgcn_sched_barrier(0);
      bf16x8 ap = *(const bf16x8*)(&Pl[wv][r16 * 40 + g * 8]);
#pragma unroll
      for (int n = 0; n < 4; ++n) {
        bf16x8 bv = *(const bf16x8*)(&Vl[(16 * n + r16) * 40 + g * 8]);
        o[n] = __builtin_amdgcn_mfma_f32_16x16x32_bf16(ap, bv, o[n], 0, 0, 0);
      }
    }
    __syncthreads();
  }

  float inv[4];
#pragma unroll
  for (int j = 0; j < 4; ++j) inv[j] = 1.0f / l[j];
#pragma unroll
  for (int n = 0; n < 4; ++n)
#pragma unroll
    for (int j = 0; j < 4; ++j)
      AO[(size_t)(b * S_ + qbase + 4 * g + j) * D_ + h * DH_ + 16 * n + r16] =
          f2bf(o[n][j] * inv[j]);
}

// ---------------- output projection ----------------
// out[M=8192,N=1024] = AO(bf16) @ W^T + b ; grid (16 ntiles, 128 mtiles)
__global__ __launch_bounds__(256) void gemm_out(
    const ushort* __restrict__ A, const ushort* __restrict__ Wb,
    const float* __restrict__ bO, float* __restrict__ out) {
  __shared__ ushort Wl[64 * 72];
  const int n0 = blockIdx.x * 64;
  const int m0 = blockIdx.y * 64;
  const int tid = threadIdx.x;
  const int wv = tid >> 6, ln = tid & 63;
  const int r16 = ln & 15, g = ln >> 4;
  f32x4 acc[4] = {};
  const ushort* arow = A + (size_t)(m0 + wv * 16 + r16) * D_;

  for (int kk = 0; kk < D_; kk += 64) {
    {
      int row = tid >> 3, seg = tid & 7;   // rows 0..31
      *(bf16x8*)(&Wl[row * 72 + seg * 8]) =
          *(const bf16x8*)(Wb + (size_t)(n0 + row) * D_ + kk + seg * 8);
      int row2 = row + 32;                 // rows 32..63
      *(bf16x8*)(&Wl[row2 * 72 + seg * 8]) =
          *(const bf16x8*)(Wb + (size_t)(n0 + row2) * D_ + kk + seg * 8);
    }
    __syncthreads();
    bf16x8 a0 = *(const bf16x8*)(arow + kk + g * 8);
    bf16x8 a1 = *(const bf16x8*)(arow + kk + 32 + g * 8);
#pragma unroll
    for (int n = 0; n < 4; ++n) {
      bf16x8 w0 = *(const bf16x8*)(&Wl[(16 * n + r16) * 72 + g * 8]);
      bf16x8 w1 = *(const bf16x8*)(&Wl[(16 * n + r16) * 72 + 32 + g * 8]);
      acc[n] = __builtin_amdgcn_mfma_f32_16x16x32_bf16(a0, w0, acc[n], 0, 0, 0);
      acc[n] = __builtin_amdgcn_mfma_f32_16x16x32_bf16(a1, w1, acc[n], 0, 0, 0);
    }
    __syncthreads();
  }
#pragma unroll
  for (int n = 0; n < 4; ++n) {
    float bb = bO[n0 + 16 * n + r16];
#pragma unroll
    for (int j = 0; j < 4; ++j) {
      out[(size_t)(m0 + wv * 16 + 4 * g + j) * D_ + n0 + 16 * n + r16] = acc[n][j] + bb;
    }
  }
}

extern "C" void kernel_launch(void* const* d_in, const int* in_sizes, int n_in,
                              void* d_out, int out_size, void* d_ws, size_t ws_size,
                              hipStream_t stream) {
  const float* q = (const float*)d_in[0];
  const float* k = (const float*)d_in[1];
  const float* v = (const float*)d_in[2];
  const int* kpm = (const int*)d_in[3];
  const float* W = (const float*)d_in[4];
  const float* bO = (const float*)d_in[5];

  char* ws = (char*)d_ws;
  const size_t SZ = (size_t)B_ * S_ * D_ * 2;      // 16 MB
  ushort* Kb = (ushort*)ws;                        // [B,S,D] bf16
  ushort* Vt = (ushort*)(ws + SZ);                 // [B,H,DH,S] bf16
  ushort* AO = (ushort*)(ws + 2 * SZ);             // [B,S,D] bf16
  ushort* Wb = (ushort*)(ws + 3 * SZ);             // [D,D] bf16 (2 MB)
  float* MF = (float*)(ws + 3 * SZ + (size_t)D_ * D_ * 2);  // [B,S] f32

  cast_k_kernel<<<8192, 256, 0, stream>>>(k, Kb);
  cast_w_kernel<<<1024, 256, 0, stream>>>(W, Wb);
  mask_kernel<<<32, 256, 0, stream>>>(kpm, MF);
  transpose_v_kernel<<<2048, 256, 0, stream>>>(v, Vt);
  attn_fwd<<<dim3(32, H_, B_), 256, 0, stream>>>(q, Kb, Vt, MF, AO);
  gemm_out<<<dim3(16, 128), 256, 0, stream>>>(AO, Wb, bO, (float*)d_out);
}

// Round 2
// 212.680 us; speedup vs baseline: 1.8306x; 1.8306x over previous
//
#include <hip/hip_runtime.h>
#include <hip/hip_bf16.h>

#define B_ 4
#define S_ 2048
#define D_ 1024
#define H_ 16
#define DH_ 64

typedef __attribute__((ext_vector_type(8))) short bf16x8;
typedef __attribute__((ext_vector_type(4))) float f32x4;
typedef __attribute__((ext_vector_type(16))) float f32x16;
typedef unsigned int uint32;

__device__ __forceinline__ unsigned short f2bf(float f) {
  unsigned int u = __float_as_uint(f);
  u += 0x7FFFu + ((u >> 16) & 1u);
  return (unsigned short)(u >> 16);
}

// truncating pack of two f32 -> (bf16,bf16) in one v_perm_b32
__device__ __forceinline__ uint32 pk2(float lo, float hi) {
  return __builtin_amdgcn_perm(__float_as_uint(hi), __float_as_uint(lo), 0x07060302u);
}

// ---------------- prep kernels ----------------

__global__ void cast_k_kernel(const float* __restrict__ k, ushort* __restrict__ Kb) {
  int i = blockIdx.x * 256 + threadIdx.x;
  float4 a = ((const float4*)k)[i];
  ushort4 r;
  r.x = f2bf(a.x); r.y = f2bf(a.y); r.z = f2bf(a.z); r.w = f2bf(a.w);
  ((ushort4*)Kb)[i] = r;
}

__global__ void cast_w_kernel(const float* __restrict__ w, ushort* __restrict__ Wb) {
  int i = blockIdx.x * 256 + threadIdx.x;
  float4 a = ((const float4*)w)[i];
  ushort4 r;
  r.x = f2bf(a.x); r.y = f2bf(a.y); r.z = f2bf(a.z); r.w = f2bf(a.w);
  ((ushort4*)Wb)[i] = r;
}

// mask (int 0/1 [B,S]) -> float addend {0,-1e30} + per-64-key-block any-flag
__global__ void mask_kernel(const int* __restrict__ kpm, float* __restrict__ MF,
                            int* __restrict__ anyM) {
  int i = blockIdx.x * 256 + threadIdx.x;   // 8192
  int m = kpm[i];
  MF[i] = m ? -1e30f : 0.0f;
  unsigned long long bal = __ballot(m != 0);
  if ((i & 63) == 0) anyM[i >> 6] = (bal != 0ull) ? 1 : 0;
}

// V (fp32 [B,S,H*DH]) -> Vt (bf16 [B,H,DH,S])
__global__ void transpose_v_kernel(const float* __restrict__ v, ushort* __restrict__ Vt) {
  __shared__ ushort tile[64][68];
  int bh = blockIdx.x >> 5;
  int s0 = (blockIdx.x & 31) << 6;
  int b = bh >> 4, h = bh & 15;
  int t = threadIdx.x;
#pragma unroll
  for (int it = 0; it < 16; ++it) {
    int r = it * 4 + (t >> 6);
    int c = t & 63;
    float x = v[(size_t)(b * S_ + s0 + r) * D_ + h * DH_ + c];
    tile[r][c] = f2bf(x);
  }
  __syncthreads();
#pragma unroll
  for (int it = 0; it < 16; ++it) {
    int d = it * 4 + (t >> 6);
    int s = t & 63;
    Vt[(size_t)(bh * DH_ + d) * S_ + s0 + s] = tile[s][d];
  }
}

// ---------------- flash attention (32x32 swapped-operand structure) ----------------
// grid (S/128, H, B), 256 threads = 4 waves; wave owns 32 q rows; KVBLK=64.
__global__ __launch_bounds__(256, 3) void attn_fwd(
    const float* __restrict__ q, const ushort* __restrict__ Kb,
    const ushort* __restrict__ Vt, const float* __restrict__ MF,
    const int* __restrict__ anyM, ushort* __restrict__ AO) {
  __shared__ ushort lds[2][2][64 * 64];   // [buf][K/V][64 rows x 64 cols], XOR-swizzled

  const int b = blockIdx.z, h = blockIdx.y;
  const int q0 = blockIdx.x * 128;
  const int tid = threadIdx.x;
  const int wv = tid >> 6, ln = tid & 63;
  const int q32 = ln & 31;          // q column owned by this lane (swapped layout)
  const int hi = ln >> 5;
  const int l7 = ln & 7, l3 = ln >> 3;
  const int qw0 = q0 + wv * 32;
  const float SC = 0.18033688011112042f;  // 0.125 * log2(e)

  // Q fragments: qf[j][i] = Q[qw0+q32][16j + 8hi + i]   (B operand of QK^T)
  bf16x8 qf[4];
  {
    const float* qp = q + (size_t)(b * S_ + qw0 + q32) * D_ + h * DH_ + hi * 8;
#pragma unroll
    for (int j = 0; j < 4; ++j) {
      float4 x0 = *(const float4*)(qp + 16 * j);
      float4 x1 = *(const float4*)(qp + 16 * j + 4);
      bf16x8 t;
      t[0] = (short)f2bf(x0.x); t[1] = (short)f2bf(x0.y);
      t[2] = (short)f2bf(x0.z); t[3] = (short)f2bf(x0.w);
      t[4] = (short)f2bf(x1.x); t[5] = (short)f2bf(x1.y);
      t[6] = (short)f2bf(x1.z); t[7] = (short)f2bf(x1.w);
      qf[j] = t;
    }
  }

  const ushort* Kg = Kb + (size_t)b * S_ * D_ + h * DH_;
  const ushort* Vg = Vt + (size_t)((b * H_ + h) * DH_) * S_;

  bf16x8 kst[2], vst[2];                 // staging regs (issue-early, write-late)
  const int wrow0 = 16 * wv + l3;        // this lane's staging rows: wrow0, wrow0+8
  const int wss = (l7 ^ l3) * 8;         // swizzled 16B slot within row

  auto loadTile = [&](int kt) {
#pragma unroll
    for (int p = 0; p < 2; ++p) {
      int row = wrow0 + 8 * p;
      kst[p] = *(const bf16x8*)(Kg + (size_t)(kt * 64 + row) * D_ + l7 * 8);
      vst[p] = *(const bf16x8*)(Vg + (size_t)row * S_ + kt * 64 + l7 * 8);
    }
  };
  auto writeTile = [&](int buf) {
#pragma unroll
    for (int p = 0; p < 2; ++p) {
      int row = wrow0 + 8 * p;
      *(bf16x8*)(&lds[buf][0][row * 64 + wss]) = kst[p];
      *(bf16x8*)(&lds[buf][1][row * 64 + wss]) = vst[p];
    }
  };
  auto packTile = [&](const f32x16& pv, bf16x8* out) {
#pragma unroll
    for (int kk = 0; kk < 2; ++kk) {
      uint32 a  = pk2(pv[8 * kk + 0], pv[8 * kk + 1]);
      uint32 c  = pk2(pv[8 * kk + 2], pv[8 * kk + 3]);
      uint32 bb = pk2(pv[8 * kk + 4], pv[8 * kk + 5]);
      uint32 dd = pk2(pv[8 * kk + 6], pv[8 * kk + 7]);
      uint32 as = __shfl_xor(a, 32), cs = __shfl_xor(c, 32);
      uint32 bs = __shfl_xor(bb, 32), ds = __shfl_xor(dd, 32);
      union { uint32 u[4]; bf16x8 v; } w;
      w.u[0] = hi ? bs : a;
      w.u[1] = hi ? ds : c;
      w.u[2] = hi ? bb : as;
      w.u[3] = hi ? dd : cs;
      out[kk] = w.v;
    }
  };

  f32x16 ot0, ot1;
#pragma unroll
  for (int i = 0; i < 16; ++i) { ot0[i] = 0.f; ot1[i] = 0.f; }
  float m_run = -1e30f, l_run = 0.f;

  const int nkb = (q0 >> 6) + 2;
  loadTile(0);
  writeTile(0);
  loadTile(1);
  __syncthreads();

  for (int t = 0; t < nkb; ++t) {
    const int cur = t & 1;
    if (t + 1 < nkb) writeTile(cur ^ 1);   // write-late (prev iter's loads)
    if (t + 2 < nkb) loadTile(t + 2);      // issue-early
    const int k0 = t * 64;
    const ushort* Kl = lds[cur][0];
    const ushort* Vl = lds[cur][1];
    const int qb = qw0 >> 5;
    const bool a0 = (2 * t) <= qb, a1 = (2 * t + 1) <= qb;
    const bool dg0 = (2 * t) == qb, dg1 = (2 * t + 1) == qb;
    const int flag = anyM[b * 32 + t];

    f32x16 s0v, s1v;
    if (a0) {
#pragma unroll
      for (int i = 0; i < 16; ++i) s0v[i] = 0.f;
#pragma unroll
      for (int j = 0; j < 4; ++j) {
        bf16x8 kf = *(const bf16x8*)(&Kl[q32 * 64 + (((2 * j + hi) ^ l7) * 8)]);
        s0v = __builtin_amdgcn_mfma_f32_32x32x16_bf16(kf, qf[j], s0v, 0, 0, 0);
      }
    }
    if (a1) {
#pragma unroll
      for (int i = 0; i < 16; ++i) s1v[i] = 0.f;
#pragma unroll
      for (int j = 0; j < 4; ++j) {
        bf16x8 kf = *(const bf16x8*)(&Kl[(32 + q32) * 64 + (((2 * j + hi) ^ l7) * 8)]);
        s1v = __builtin_amdgcn_mfma_f32_32x32x16_bf16(kf, qf[j], s1v, 0, 0, 0);
      }
    }

    // ---- online softmax, all per-lane (lane owns q-row) ----
    float mx = -3.0e38f;
    if (a0) {
#pragma unroll
      for (int r = 0; r < 16; ++r) {
        int cr = (r & 3) + 8 * (r >> 2) + 4 * hi;
        float s = s0v[r] * SC;
        if (flag) s += MF[b * S_ + k0 + cr];
        if (dg0 && cr > q32) s = -3.0e38f;
        s0v[r] = s;
        mx = fmaxf(mx, s);
      }
    }
    if (a1) {
#pragma unroll
      for (int r = 0; r < 16; ++r) {
        int cr = (r & 3) + 8 * (r >> 2) + 4 * hi;
        float s = s1v[r] * SC;
        if (flag) s += MF[b * S_ + k0 + 32 + cr];
        if (dg1 && cr > q32) s = -3.0e38f;
        s1v[r] = s;
        mx = fmaxf(mx, s);
      }
    }
    mx = fmaxf(mx, __shfl_xor(mx, 32));
    const float mn = fmaxf(m_run, mx);
    const float fac = __builtin_amdgcn_exp2f(m_run - mn);
    m_run = mn;
    float rs = 0.f;
    if (a0) {
#pragma unroll
      for (int r = 0; r < 16; ++r) {
        float p = __builtin_amdgcn_exp2f(s0v[r] - mn);
        s0v[r] = p; rs += p;
      }
    }
    if (a1) {
#pragma unroll
      for (int r = 0; r < 16; ++r) {
        float p = __builtin_amdgcn_exp2f(s1v[r] - mn);
        s1v[r] = p; rs += p;
      }
    }
    rs += __shfl_xor(rs, 32);
    l_run = l_run * fac + rs;
#pragma unroll
    for (int r = 0; r < 16; ++r) { ot0[r] *= fac; ot1[r] *= fac; }

    bf16x8 pa[4];
    if (a0) packTile(s0v, &pa[0]);
    if (a1) packTile(s1v, &pa[2]);

#pragma unroll
    for (int dt = 0; dt < 2; ++dt) {
      f32x16& ot = dt ? ot1 : ot0;
      const int rowb = (dt * 32 + q32) * 64;
      if (a0) {
        bf16x8 v0 = *(const bf16x8*)(&Vl[rowb + (((0 + hi) ^ l7) * 8)]);
        ot = __builtin_amdgcn_mfma_f32_32x32x16_bf16(v0, pa[0], ot, 0, 0, 0);
        bf16x8 v1 = *(const bf16x8*)(&Vl[rowb + (((2 + hi) ^ l7) * 8)]);
        ot = __builtin_amdgcn_mfma_f32_32x32x16_bf16(v1, pa[1], ot, 0, 0, 0);
      }
      if (a1) {
        bf16x8 v2 = *(const bf16x8*)(&Vl[rowb + (((4 + hi) ^ l7) * 8)]);
        ot = __builtin_amdgcn_mfma_f32_32x32x16_bf16(v2, pa[2], ot, 0, 0, 0);
        bf16x8 v3 = *(const bf16x8*)(&Vl[rowb + (((6 + hi) ^ l7) * 8)]);
        ot = __builtin_amdgcn_mfma_f32_32x32x16_bf16(v3, pa[3], ot, 0, 0, 0);
      }
    }
    __syncthreads();
  }

  // ---- epilogue: normalize, LDS transpose (swizzled), coalesced store ----
  const float inv = __builtin_amdgcn_rcpf(l_run);
  ushort* tb = ((ushort*)lds) + wv * 2048;   // 4KB per wave
#pragma unroll
  for (int dt = 0; dt < 2; ++dt) {
    const f32x16& ot = dt ? ot1 : ot0;
#pragma unroll
    for (int rp = 0; rp < 8; ++rp) {
      int r0 = rp * 2;
      int d0 = dt * 32 + (r0 & 3) + 8 * (r0 >> 2) + 4 * hi;
      uint32 w = pk2(ot[r0] * inv, ot[r0 + 1] * inv);
      int e = q32 * 64 + (((d0 >> 3) ^ (q32 & 7)) * 8) + (d0 & 7);
      *(uint32*)(&tb[e]) = w;
    }
  }
  __syncthreads();
#pragma unroll
  for (int it = 0; it < 4; ++it) {
    int qq = it * 8 + l3;
    bf16x8 val = *(const bf16x8*)(&tb[qq * 64 + ((l7 ^ (qq & 7)) * 8)]);
    *(bf16x8*)(AO + (size_t)(b * S_ + qw0 + qq) * D_ + h * DH_ + l7 * 8) = val;
  }
}

// ---------------- output projection ----------------
__global__ __launch_bounds__(256) void gemm_out(
    const ushort* __restrict__ A, const ushort* __restrict__ Wb,
    const float* __restrict__ bO, float* __restrict__ out) {
  __shared__ ushort Wl[64 * 72];
  const int n0 = blockIdx.x * 64;
  const int m0 = blockIdx.y * 64;
  const int tid = threadIdx.x;
  const int wv = tid >> 6, ln = tid & 63;
  const int r16 = ln & 15, g = ln >> 4;
  f32x4 acc[4] = {};
  const ushort* arow = A + (size_t)(m0 + wv * 16 + r16) * D_;

  for (int kk = 0; kk < D_; kk += 64) {
    {
      int row = tid >> 3, seg = tid & 7;
      *(bf16x8*)(&Wl[row * 72 + seg * 8]) =
          *(const bf16x8*)(Wb + (size_t)(n0 + row) * D_ + kk + seg * 8);
      int row2 = row + 32;
      *(bf16x8*)(&Wl[row2 * 72 + seg * 8]) =
          *(const bf16x8*)(Wb + (size_t)(n0 + row2) * D_ + kk + seg * 8);
    }
    __syncthreads();
    bf16x8 a0 = *(const bf16x8*)(arow + kk + g * 8);
    bf16x8 a1 = *(const bf16x8*)(arow + kk + 32 + g * 8);
#pragma unroll
    for (int n = 0; n < 4; ++n) {
      bf16x8 w0 = *(const bf16x8*)(&Wl[(16 * n + r16) * 72 + g * 8]);
      bf16x8 w1 = *(const bf16x8*)(&Wl[(16 * n + r16) * 72 + 32 + g * 8]);
      acc[n] = __builtin_amdgcn_mfma_f32_16x16x32_bf16(a0, w0, acc[n], 0, 0, 0);
      acc[n] = __builtin_amdgcn_mfma_f32_16x16x32_bf16(a1, w1, acc[n], 0, 0, 0);
    }
    __syncthreads();
  }
#pragma unroll
  for (int n = 0; n < 4; ++n) {
    float bb = bO[n0 + 16 * n + r16];
#pragma unroll
    for (int j = 0; j < 4; ++j) {
      out[(size_t)(m0 + wv * 16 + 4 * g + j) * D_ + n0 + 16 * n + r16] = acc[n][j] + bb;
    }
  }
}

extern "C" void kernel_launch(void* const* d_in, const int* in_sizes, int n_in,
                              void* d_out, int out_size, void* d_ws, size_t ws_size,
                              hipStream_t stream) {
  const float* q = (const float*)d_in[0];
  const float* k = (const float*)d_in[1];
  const float* v = (const float*)d_in[2];
  const int* kpm = (const int*)d_in[3];
  const float* W = (const float*)d_in[4];
  const float* bO = (const float*)d_in[5];

  char* ws = (char*)d_ws;
  const size_t SZ = (size_t)B_ * S_ * D_ * 2;      // 16 MB
  ushort* Kb = (ushort*)ws;                        // [B,S,D] bf16
  ushort* Vt = (ushort*)(ws + SZ);                 // [B,H,DH,S] bf16
  ushort* AO = (ushort*)(ws + 2 * SZ);             // [B,S,D] bf16
  ushort* Wb = (ushort*)(ws + 3 * SZ);             // [D,D] bf16
  float* MF = (float*)(ws + 3 * SZ + (size_t)D_ * D_ * 2);            // [B,S] f32
  int* anyM = (int*)(ws + 3 * SZ + (size_t)D_ * D_ * 2 + (size_t)B_ * S_ * 4);  // [B,32]

  cast_k_kernel<<<8192, 256, 0, stream>>>(k, Kb);
  cast_w_kernel<<<1024, 256, 0, stream>>>(W, Wb);
  mask_kernel<<<32, 256, 0, stream>>>(kpm, MF, anyM);
  transpose_v_kernel<<<2048, 256, 0, stream>>>(v, Vt);
  attn_fwd<<<dim3(16, H_, B_), 256, 0, stream>>>(q, Kb, Vt, MF, anyM, AO);
  gemm_out<<<dim3(16, 128), 256, 0, stream>>>(AO, Wb, bO, (float*)d_out);
}

// Round 4
// 126.443 us; speedup vs baseline: 3.0790x; 1.6820x over previous
//
#include <hip/hip_runtime.h>
#include <hip/hip_bf16.h>

#define B_ 4
#define S_ 2048
#define D_ 1024
#define H_ 16
#define DH_ 64

typedef __attribute__((ext_vector_type(8))) short bf16x8;
typedef __attribute__((ext_vector_type(4))) float f32x4;
typedef __attribute__((ext_vector_type(16))) float f32x16;
typedef __attribute__((ext_vector_type(2))) int v2i;
typedef unsigned int uint32;

__device__ __forceinline__ unsigned short f2bf(float f) {
  unsigned int u = __float_as_uint(f);
  u += 0x7FFFu + ((u >> 16) & 1u);
  return (unsigned short)(u >> 16);
}

// truncating pack of two f32 -> (bf16,bf16) in one v_perm_b32
__device__ __forceinline__ uint32 pk2(float lo, float hi) {
  return __builtin_amdgcn_perm(__float_as_uint(hi), __float_as_uint(lo), 0x07060302u);
}

// combine with lane^32 partner: returns (self-ish, partner-ish) pair via permlane32_swap
__device__ __forceinline__ float half_max(float v) {
  v2i r = __builtin_amdgcn_permlane32_swap(__float_as_int(v), __float_as_int(v), false, false);
  return fmaxf(__int_as_float(r[0]), __int_as_float(r[1]));
}
__device__ __forceinline__ float half_add(float v) {
  v2i r = __builtin_amdgcn_permlane32_swap(__float_as_int(v), __float_as_int(v), false, false);
  return __int_as_float(r[0]) + __int_as_float(r[1]);
}

// ---------------- prep kernels ----------------

__global__ void cast_k_kernel(const float* __restrict__ k, ushort* __restrict__ Kb) {
  int i = blockIdx.x * 256 + threadIdx.x;
  float4 a = ((const float4*)k)[i];
  ushort4 r;
  r.x = f2bf(a.x); r.y = f2bf(a.y); r.z = f2bf(a.z); r.w = f2bf(a.w);
  ((ushort4*)Kb)[i] = r;
}

__global__ void cast_w_kernel(const float* __restrict__ w, ushort* __restrict__ Wb) {
  int i = blockIdx.x * 256 + threadIdx.x;
  float4 a = ((const float4*)w)[i];
  ushort4 r;
  r.x = f2bf(a.x); r.y = f2bf(a.y); r.z = f2bf(a.z); r.w = f2bf(a.w);
  ((ushort4*)Wb)[i] = r;
}

__global__ void mask_kernel(const int* __restrict__ kpm, float* __restrict__ MF,
                            int* __restrict__ anyM) {
  int i = blockIdx.x * 256 + threadIdx.x;   // 8192
  int m = kpm[i];
  MF[i] = m ? -1e30f : 0.0f;
  unsigned long long bal = __ballot(m != 0);
  if ((i & 63) == 0) anyM[i >> 6] = (bal != 0ull) ? 1 : 0;
}

// V (fp32 [B,S,H*DH]) -> Vt (bf16 [B,H,DH,S])
__global__ void transpose_v_kernel(const float* __restrict__ v, ushort* __restrict__ Vt) {
  __shared__ ushort tile[64][68];
  int bh = blockIdx.x >> 5;
  int s0 = (blockIdx.x & 31) << 6;
  int b = bh >> 4, h = bh & 15;
  int t = threadIdx.x;
#pragma unroll
  for (int it = 0; it < 16; ++it) {
    int r = it * 4 + (t >> 6);
    int c = t & 63;
    float x = v[(size_t)(b * S_ + s0 + r) * D_ + h * DH_ + c];
    tile[r][c] = f2bf(x);
  }
  __syncthreads();
#pragma unroll
  for (int it = 0; it < 16; ++it) {
    int d = it * 4 + (t >> 6);
    int s = t & 63;
    Vt[(size_t)(bh * DH_ + d) * S_ + s0 + s] = tile[s][d];
  }
}

// ---------------- flash attention (32x32 swapped-operand, zigzag-paired) ----------------
// grid (8 pairs, H, B); block does q-tiles x and 15-x (uniform 34 k-iters).
__global__ __launch_bounds__(256, 2) void attn_fwd(
    const float* __restrict__ q, const ushort* __restrict__ Kb,
    const ushort* __restrict__ Vt, const float* __restrict__ MF,
    const int* __restrict__ anyM, ushort* __restrict__ AO) {
  __shared__ ushort lds[2][2][64 * 64];   // [buf][K/V][64 x 64], XOR-swizzled

  const int b = blockIdx.z, h = blockIdx.y;
  const int xx = blockIdx.x;
  const int tid = threadIdx.x;
  const int wv = tid >> 6, ln = tid & 63;
  const int q32 = ln & 31;
  const int hi = ln >> 5;
  const int l7 = ln & 7, l3 = ln >> 3;
  const float SC = 0.18033688011112042f;  // 0.125 * log2(e), folded into Q
  const int cr4 = 4 * hi;

  const ushort* Kg = Kb + (size_t)b * S_ * D_ + h * DH_;
  const ushort* Vg = Vt + (size_t)((b * H_ + h) * DH_) * S_;

  bf16x8 kst[2], vst[2];
  const int wrow0 = 16 * wv + l3;
  const int wss = (l7 ^ l3) * 8;

  auto loadTile = [&](int kt) {
#pragma unroll
    for (int p = 0; p < 2; ++p) {
      int row = wrow0 + 8 * p;
      kst[p] = *(const bf16x8*)(Kg + (size_t)(kt * 64 + row) * D_ + l7 * 8);
      vst[p] = *(const bf16x8*)(Vg + (size_t)row * S_ + kt * 64 + l7 * 8);
    }
  };
  auto writeTile = [&](int buf) {
#pragma unroll
    for (int p = 0; p < 2; ++p) {
      int row = wrow0 + 8 * p;
      *(bf16x8*)(&lds[buf][0][row * 64 + wss]) = kst[p];
      *(bf16x8*)(&lds[buf][1][row * 64 + wss]) = vst[p];
    }
  };
  // P f32x16 -> 2 B-fragments via 4 pk2 + 2 permlane32_swap per chunk
  auto packTile = [&](const f32x16& pv, bf16x8* out) {
#pragma unroll
    for (int kk = 0; kk < 2; ++kk) {
      uint32 a  = pk2(pv[8 * kk + 0], pv[8 * kk + 1]);
      uint32 c  = pk2(pv[8 * kk + 2], pv[8 * kk + 3]);
      uint32 bb = pk2(pv[8 * kk + 4], pv[8 * kk + 5]);
      uint32 dd = pk2(pv[8 * kk + 6], pv[8 * kk + 7]);
      v2i r0 = __builtin_amdgcn_permlane32_swap((int)a, (int)bb, false, false);
      v2i r1 = __builtin_amdgcn_permlane32_swap((int)c, (int)dd, false, false);
      union { uint32 u[4]; bf16x8 v; } w;
      w.u[0] = (uint32)r0[0]; w.u[1] = (uint32)r1[0];
      w.u[2] = (uint32)r0[1]; w.u[3] = (uint32)r1[1];
      out[kk] = w.v;
    }
  };

  for (int half = 0; half < 2; ++half) {
    const int q0 = (half ? (15 - xx) : xx) * 128;
    const int qw0 = q0 + wv * 32;
    const int qb = qw0 >> 5;

    // Q fragments, pre-scaled by SC
    bf16x8 qf[4];
    {
      const float* qp = q + (size_t)(b * S_ + qw0 + q32) * D_ + h * DH_ + hi * 8;
#pragma unroll
      for (int j = 0; j < 4; ++j) {
        float4 x0 = *(const float4*)(qp + 16 * j);
        float4 x1 = *(const float4*)(qp + 16 * j + 4);
        bf16x8 t;
        t[0] = (short)f2bf(x0.x * SC); t[1] = (short)f2bf(x0.y * SC);
        t[2] = (short)f2bf(x0.z * SC); t[3] = (short)f2bf(x0.w * SC);
        t[4] = (short)f2bf(x1.x * SC); t[5] = (short)f2bf(x1.y * SC);
        t[6] = (short)f2bf(x1.z * SC); t[7] = (short)f2bf(x1.w * SC);
        qf[j] = t;
      }
    }

    f32x16 ot0, ot1;
#pragma unroll
    for (int i = 0; i < 16; ++i) { ot0[i] = 0.f; ot1[i] = 0.f; }
    float m_run = -1e30f, l_run = 0.f;

    const int nkb = (q0 >> 6) + 2;
    loadTile(0);
    writeTile(0);
    if (nkb > 1) loadTile(1);
    __syncthreads();

    for (int t = 0; t < nkb; ++t) {
      const int cur = t & 1;
      if (t + 1 < nkb) writeTile(cur ^ 1);
      if (t + 2 < nkb) loadTile(t + 2);
      const int k0 = t * 64;
      const ushort* Kl = lds[cur][0];
      const ushort* Vl = lds[cur][1];
      const bool a0 = (2 * t) <= qb, a1 = (2 * t + 1) <= qb;
      const bool dg0 = (2 * t) == qb, dg1 = (2 * t + 1) == qb;
      const int flag = anyM[b * 32 + t];

      f32x16 s0v, s1v;
      if (a0) {
#pragma unroll
        for (int i = 0; i < 16; ++i) s0v[i] = 0.f;
#pragma unroll
        for (int j = 0; j < 4; ++j) {
          bf16x8 kf = *(const bf16x8*)(&Kl[q32 * 64 + (((2 * j + hi) ^ l7) * 8)]);
          s0v = __builtin_amdgcn_mfma_f32_32x32x16_bf16(kf, qf[j], s0v, 0, 0, 0);
        }
      }
      if (a1) {
#pragma unroll
        for (int i = 0; i < 16; ++i) s1v[i] = 0.f;
#pragma unroll
        for (int j = 0; j < 4; ++j) {
          bf16x8 kf = *(const bf16x8*)(&Kl[(32 + q32) * 64 + (((2 * j + hi) ^ l7) * 8)]);
          s1v = __builtin_amdgcn_mfma_f32_32x32x16_bf16(kf, qf[j], s1v, 0, 0, 0);
        }
      }

      if (a0 || a1) {
        float mxa = -3.0e38f, mxb = -3.0e38f;
        if (a0) {
#pragma unroll
          for (int r = 0; r < 16; ++r) {
            int cr = (r & 3) + 8 * (r >> 2) + cr4;
            float s = s0v[r];
            if (flag) s += MF[b * S_ + k0 + cr];
            if (dg0 && cr > q32) s = -3.0e38f;
            s0v[r] = s;
            if (r & 1) mxb = fmaxf(mxb, s); else mxa = fmaxf(mxa, s);
          }
        }
        if (a1) {
#pragma unroll
          for (int r = 0; r < 16; ++r) {
            int cr = (r & 3) + 8 * (r >> 2) + cr4;
            float s = s1v[r];
            if (flag) s += MF[b * S_ + k0 + 32 + cr];
            if (dg1 && cr > q32) s = -3.0e38f;
            s1v[r] = s;
            if (r & 1) mxb = fmaxf(mxb, s); else mxa = fmaxf(mxa, s);
          }
        }
        float mx = half_max(fmaxf(mxa, mxb));
        const bool doresc = __any(mx - m_run > 8.0f);
        float fac = 1.0f;
        if (doresc) {
          float mn = fmaxf(m_run, mx);
          fac = __builtin_amdgcn_exp2f(m_run - mn);
          m_run = mn;
        }
        float rsa = 0.f, rsb = 0.f;
        if (a0) {
#pragma unroll
          for (int r = 0; r < 16; ++r) {
            float p = __builtin_amdgcn_exp2f(s0v[r] - m_run);
            s0v[r] = p;
            if (r & 1) rsb += p; else rsa += p;
          }
        }
        if (a1) {
#pragma unroll
          for (int r = 0; r < 16; ++r) {
            float p = __builtin_amdgcn_exp2f(s1v[r] - m_run);
            s1v[r] = p;
            if (r & 1) rsb += p; else rsa += p;
          }
        }
        float rs = half_add(rsa + rsb);
        if (doresc) {
          l_run = l_run * fac + rs;
#pragma unroll
          for (int r = 0; r < 16; ++r) { ot0[r] *= fac; ot1[r] *= fac; }
        } else {
          l_run += rs;
        }

        bf16x8 pa[4];
        if (a0) packTile(s0v, &pa[0]);
        if (a1) packTile(s1v, &pa[2]);

#pragma unroll
        for (int dt = 0; dt < 2; ++dt) {
          f32x16& ot = dt ? ot1 : ot0;
          const int rowb = (dt * 32 + q32) * 64;
          if (a0) {
            bf16x8 v0 = *(const bf16x8*)(&Vl[rowb + (((0 + hi) ^ l7) * 8)]);
            ot = __builtin_amdgcn_mfma_f32_32x32x16_bf16(v0, pa[0], ot, 0, 0, 0);
            bf16x8 v1 = *(const bf16x8*)(&Vl[rowb + (((2 + hi) ^ l7) * 8)]);
            ot = __builtin_amdgcn_mfma_f32_32x32x16_bf16(v1, pa[1], ot, 0, 0, 0);
          }
          if (a1) {
            bf16x8 v2 = *(const bf16x8*)(&Vl[rowb + (((4 + hi) ^ l7) * 8)]);
            ot = __builtin_amdgcn_mfma_f32_32x32x16_bf16(v2, pa[2], ot, 0, 0, 0);
            bf16x8 v3 = *(const bf16x8*)(&Vl[rowb + (((6 + hi) ^ l7) * 8)]);
            ot = __builtin_amdgcn_mfma_f32_32x32x16_bf16(v3, pa[3], ot, 0, 0, 0);
          }
        }
      }
      __syncthreads();
    }

    // ---- epilogue: normalize, LDS transpose (swizzled), coalesced store ----
    const float inv = __builtin_amdgcn_rcpf(l_run);
    ushort* tb = ((ushort*)lds) + wv * 2048;   // 4KB per wave
#pragma unroll
    for (int dt = 0; dt < 2; ++dt) {
      const f32x16& ot = dt ? ot1 : ot0;
#pragma unroll
      for (int rp = 0; rp < 8; ++rp) {
        int r0 = rp * 2;
        int d0 = dt * 32 + (r0 & 3) + 8 * (r0 >> 2) + cr4;
        uint32 w = pk2(ot[r0] * inv, ot[r0 + 1] * inv);
        int e = q32 * 64 + (((d0 >> 3) ^ (q32 & 7)) * 8) + (d0 & 7);
        *(uint32*)(&tb[e]) = w;
      }
    }
    __syncthreads();
#pragma unroll
    for (int it = 0; it < 4; ++it) {
      int qq = it * 8 + l3;
      bf16x8 val = *(const bf16x8*)(&tb[qq * 64 + ((l7 ^ (qq & 7)) * 8)]);
      *(bf16x8*)(AO + (size_t)(b * S_ + qw0 + qq) * D_ + h * DH_ + l7 * 8) = val;
    }
    __syncthreads();   // protect tb/lds before next half restages
  }
}

// ---------------- output projection: 128x128 tile, A+W LDS-staged (swizzled) ----------------
__global__ __launch_bounds__(256, 2) void gemm_out(
    const ushort* __restrict__ A, const ushort* __restrict__ Wb,
    const float* __restrict__ bO, float* __restrict__ out) {
  __shared__ ushort Al[128 * 64];
  __shared__ ushort Wl[128 * 64];
  const int n0 = blockIdx.x * 128;
  const int m0 = blockIdx.y * 128;
  const int tid = threadIdx.x;
  const int wv = tid >> 6, ln = tid & 63;
  const int r16 = ln & 15, g = ln >> 4;
  const int wm = wv >> 1, wn = wv & 1;
  const int trow = tid >> 3, tslot = tid & 7;
  f32x4 acc[4][4] = {};

  for (int kk = 0; kk < D_; kk += 64) {
#pragma unroll
    for (int p = 0; p < 4; ++p) {
      int row = trow + 32 * p;
      int soff = (tslot ^ (row & 7)) * 8;
      *(bf16x8*)(&Al[row * 64 + soff]) =
          *(const bf16x8*)(A + (size_t)(m0 + row) * D_ + kk + tslot * 8);
      *(bf16x8*)(&Wl[row * 64 + soff]) =
          *(const bf16x8*)(Wb + (size_t)(n0 + row) * D_ + kk + tslot * 8);
    }
    __syncthreads();
#pragma unroll
    for (int hh = 0; hh < 2; ++hh) {
      bf16x8 af[4], wf[4];
#pragma unroll
      for (int m = 0; m < 4; ++m) {
        int row = 64 * wm + 16 * m + r16;
        af[m] = *(const bf16x8*)(&Al[row * 64 + (((4 * hh + g) ^ (row & 7)) * 8)]);
      }
#pragma unroll
      for (int n = 0; n < 4; ++n) {
        int row = 64 * wn + 16 * n + r16;
        wf[n] = *(const bf16x8*)(&Wl[row * 64 + (((4 * hh + g) ^ (row & 7)) * 8)]);
      }
#pragma unroll
      for (int m = 0; m < 4; ++m)
#pragma unroll
        for (int n = 0; n < 4; ++n)
          acc[m][n] = __builtin_amdgcn_mfma_f32_16x16x32_bf16(af[m], wf[n], acc[m][n], 0, 0, 0);
    }
    __syncthreads();
  }

#pragma unroll
  for (int n = 0; n < 4; ++n) {
    float bb = bO[n0 + 64 * wn + 16 * n + r16];
#pragma unroll
    for (int m = 0; m < 4; ++m) {
#pragma unroll
      for (int j = 0; j < 4; ++j) {
        out[(size_t)(m0 + 64 * wm + 16 * m + 4 * g + j) * D_ + n0 + 64 * wn + 16 * n + r16] =
            acc[m][n][j] + bb;
      }
    }
  }
}

extern "C" void kernel_launch(void* const* d_in, const int* in_sizes, int n_in,
                              void* d_out, int out_size, void* d_ws, size_t ws_size,
                              hipStream_t stream) {
  const float* q = (const float*)d_in[0];
  const float* k = (const float*)d_in[1];
  const float* v = (const float*)d_in[2];
  const int* kpm = (const int*)d_in[3];
  const float* W = (const float*)d_in[4];
  const float* bO = (const float*)d_in[5];

  char* ws = (char*)d_ws;
  const size_t SZ = (size_t)B_ * S_ * D_ * 2;      // 16 MB
  ushort* Kb = (ushort*)ws;                        // [B,S,D] bf16
  ushort* Vt = (ushort*)(ws + SZ);                 // [B,H,DH,S] bf16
  ushort* AO = (ushort*)(ws + 2 * SZ);             // [B,S,D] bf16
  ushort* Wb = (ushort*)(ws + 3 * SZ);             // [D,D] bf16
  float* MF = (float*)(ws + 3 * SZ + (size_t)D_ * D_ * 2);            // [B,S] f32
  int* anyM = (int*)(ws + 3 * SZ + (size_t)D_ * D_ * 2 + (size_t)B_ * S_ * 4);  // [B,32]

  cast_k_kernel<<<8192, 256, 0, stream>>>(k, Kb);
  cast_w_kernel<<<1024, 256, 0, stream>>>(W, Wb);
  mask_kernel<<<32, 256, 0, stream>>>(kpm, MF, anyM);
  transpose_v_kernel<<<2048, 256, 0, stream>>>(v, Vt);
  attn_fwd<<<dim3(8, H_, B_), 256, 0, stream>>>(q, Kb, Vt, MF, anyM, AO);
  gemm_out<<<dim3(8, 64), 256, 0, stream>>>(AO, Wb, bO, (float*)d_out);
}